// Round 1
// baseline (135.795 us; speedup 1.0000x reference)
//
#include <hip/hip_runtime.h>
#include <math.h>

// GAT layer forward, B=8, N=2048, F=64.
// Key identity: e[b,i,j] = leakyrelu(c_i + d_j) is rank-structured, and since
// leakyrelu is piecewise linear with one breakpoint, softmax(e) @ Wh reduces to
// TWO threshold-set sums per row:
//   num_i = exp(c_i+M-m_i) * sum_{d_j > -c_i} exp(d_j-M) Wh_j
//         + exp(.2(c_i+M)-m_i) * sum_{d_j <= -c_i} exp(.2(d_j-M)) Wh_j
// With d sorted per batch, the set sums are suffix/prefix scans -> O(N log N)
// total instead of O(N^2 F). Row max m_i = g(c_i + M) analytically (g monotone).

#define B 8
#define N 2048
#define F 64
#define NROW (B * N)         // 16384
#define NK (N + 1)           // 2049 scan boundary entries
#define ST 65                // 64 features + 1 denominator channel

__device__ __forceinline__ unsigned int ord32(float v) {
  // monotone float->uint mapping for total order
  unsigned int u = __float_as_uint(v);
  return (u & 0x80000000u) ? ~u : (u | 0x80000000u);
}

// ---------------- kernel 1: Wh = h @ W ; c = Wh@a_src ; d = Wh@a_dst --------
__global__ __launch_bounds__(256) void k_wh(const float* __restrict__ h,
                                            const float* __restrict__ W,
                                            const float* __restrict__ a,
                                            float* __restrict__ Wh,
                                            float* __restrict__ c,
                                            float* __restrict__ d) {
  int lane = threadIdx.x & 63;
  int wid  = threadIdx.x >> 6;
  int row  = blockIdx.x * 4 + wid;        // one wave per row
  float hv = h[row * F + lane];           // coalesced; broadcast via shfl below
  float acc = 0.f;
#pragma unroll
  for (int k = 0; k < F; ++k) {
    float hk = __shfl(hv, k, 64);
    acc = fmaf(hk, W[k * F + lane], acc);
  }
  Wh[row * F + lane] = acc;
  float ps = acc * a[lane];
  float pd = acc * a[F + lane];
#pragma unroll
  for (int off = 32; off > 0; off >>= 1) {
    ps += __shfl_xor(ps, off, 64);
    pd += __shfl_xor(pd, off, 64);
  }
  if (lane == 0) { c[row] = ps; d[row] = pd; }
}

// ---------------- kernel 2: per-batch max of d ------------------------------
__global__ __launch_bounds__(256) void k_bmax(const float* __restrict__ d,
                                              float* __restrict__ M) {
  __shared__ float s[256];
  int b = blockIdx.x;
  float m = -INFINITY;
  for (int i = threadIdx.x; i < N; i += 256) m = fmaxf(m, d[b * N + i]);
  s[threadIdx.x] = m;
  __syncthreads();
  for (int o = 128; o > 0; o >>= 1) {
    if (threadIdx.x < o) s[threadIdx.x] = fmaxf(s[threadIdx.x], s[threadIdx.x + o]);
    __syncthreads();
  }
  if (threadIdx.x == 0) M[b] = s[0];
}

// ---------------- kernel 3: rank-sort d per batch (comparison counting) -----
// Wave per element j; rank = #{(d,idx) pairs < (d_j, j)} -> exact permutation,
// every output slot written exactly once (ws is poisoned each call).
__global__ __launch_bounds__(256) void k_ranksort(const float* __restrict__ d,
                                                  const float* __restrict__ M,
                                                  float* __restrict__ dsort,
                                                  int* __restrict__ perm,
                                                  float* __restrict__ E1,
                                                  float* __restrict__ E2) {
  int lane = threadIdx.x & 63;
  int wid  = threadIdx.x >> 6;
  int row  = blockIdx.x * 4 + wid;        // global element 0..16383
  int b    = row >> 11;
  int j    = row & (N - 1);
  const float* db = d + b * N;
  float dj = db[j];                        // uniform per wave -> broadcast
  unsigned long long kj = ((unsigned long long)ord32(dj) << 11) | (unsigned)j;
  int cnt = 0;
#pragma unroll 4
  for (int it = 0; it < N / 64; ++it) {
    int jj = it * 64 + lane;
    float v = db[jj];
    unsigned long long kv = ((unsigned long long)ord32(v) << 11) | (unsigned)jj;
    cnt += (kv < kj) ? 1 : 0;
  }
#pragma unroll
  for (int off = 32; off > 0; off >>= 1) cnt += __shfl_xor(cnt, off, 64);
  if (lane == 0) {
    float mb = M[b];
    int r = b * N + cnt;
    dsort[r] = dj;
    perm[r]  = j;
    E1[r] = __expf(dj - mb);               // <= 1
    E2[r] = __expf(0.2f * (dj - mb));      // <= 1
  }
}

// ---------------- kernel 4: scans ------------------------------------------
// Block per (channel o, batch b): Suf[k][o] = sum_{r>=k} E1_r * val ;
// Pre[k][o] = sum_{r<k} E2_r * val ; val = Wh[perm[r]][o] (o<64) or 1 (o==64).
// Layout [b][k][o] so the final kernel's per-row read is lane-coalesced.
__global__ __launch_bounds__(256) void k_scan(const float* __restrict__ Wh,
                                              const int* __restrict__ perm,
                                              const float* __restrict__ E1,
                                              const float* __restrict__ E2,
                                              float* __restrict__ Suf,
                                              float* __restrict__ Pre) {
  __shared__ float ls[256];
  int o = blockIdx.x;                      // 0..64
  int b = blockIdx.y;
  int t = threadIdx.x;
  int r0 = t * 8;
  const float* Whb = Wh + (size_t)b * N * F;
  float x1[8], x2[8];
#pragma unroll
  for (int q = 0; q < 8; ++q) {
    int r = r0 + q;
    int p = perm[b * N + r];
    float val = (o < F) ? Whb[p * F + o] : 1.0f;
    x1[q] = E1[b * N + r] * val;
    x2[q] = E2[b * N + r] * val;
  }
  // exclusive prefix of x2
  float lp[8]; float s2 = 0.f;
#pragma unroll
  for (int q = 0; q < 8; ++q) { s2 += x2[q]; lp[q] = s2; }
  ls[t] = s2;
  __syncthreads();
  for (int dd = 1; dd < 256; dd <<= 1) {
    float v = (t >= dd) ? ls[t - dd] : 0.f;
    __syncthreads();
    ls[t] += v;
    __syncthreads();
  }
  float excl2  = (t > 0) ? ls[t - 1] : 0.f;
  float total2 = ls[255];
  __syncthreads();                         // before LDS reuse
  // suffix of x1 (scan over reversed positions)
  float ss[8]; float s1 = 0.f;
#pragma unroll
  for (int q = 7; q >= 0; --q) { s1 += x1[q]; ss[q] = s1; }
  int rt = 255 - t;
  ls[rt] = s1;
  __syncthreads();
  for (int dd = 1; dd < 256; dd <<= 1) {
    float v = (rt >= dd) ? ls[rt - dd] : 0.f;
    __syncthreads();
    ls[rt] += v;
    __syncthreads();
  }
  float offs1 = (rt > 0) ? ls[rt - 1] : 0.f;  // sum over threads > t
  float* Sb = Suf + (size_t)b * NK * ST;
  float* Pb = Pre + (size_t)b * NK * ST;
#pragma unroll
  for (int q = 0; q < 8; ++q) {
    int r = r0 + q;
    Pb[(size_t)r * ST + o] = excl2 + (q > 0 ? lp[q - 1] : 0.f);
    Sb[(size_t)r * ST + o] = offs1 + ss[q];
  }
  if (t == 0) {
    Sb[(size_t)N * ST + o] = 0.f;
    Pb[(size_t)N * ST + o] = total2;
  }
}

// ---------------- kernel 5: combine + ELU -----------------------------------
__global__ __launch_bounds__(256) void k_final(const float* __restrict__ c,
                                               const float* __restrict__ M,
                                               const float* __restrict__ dsort,
                                               const float* __restrict__ Suf,
                                               const float* __restrict__ Pre,
                                               float* __restrict__ out) {
  int lane = threadIdx.x & 63;
  int wid  = threadIdx.x >> 6;
  int row  = blockIdx.x * 4 + wid;         // one wave per row
  int b    = row >> 11;
  float ci = c[row];
  float thr = -ci;
  const float* ds = dsort + b * N;
  // first index with ds[idx] > thr  (all lanes redundant; uniform -> broadcast)
  int lo = 0, hi = N;
  while (lo < hi) {
    int mid = (lo + hi) >> 1;
    if (ds[mid] > thr) hi = mid; else lo = mid + 1;
  }
  int k = lo;
  float cpM = ci + M[b];
  float f1, f2;                            // all exponents <= 0, no overflow
  if (cpM > 0.f) { f1 = 1.f;               f2 = __expf(-0.8f * cpM); }
  else           { f1 = __expf(0.8f * cpM); f2 = 1.f; }
  const float* Sk = Suf + ((size_t)b * NK + k) * ST;
  const float* Pk = Pre + ((size_t)b * NK + k) * ST;
  float den = f1 * Sk[F]    + f2 * Pk[F];
  float num = f1 * Sk[lane] + f2 * Pk[lane];
  float v = num / den;
  out[row * F + lane] = (v > 0.f) ? v : expm1f(v);   // ELU, alpha=1
}

// ---------------- launch -----------------------------------------------------
extern "C" void kernel_launch(void* const* d_in, const int* in_sizes, int n_in,
                              void* d_out, int out_size, void* d_ws, size_t ws_size,
                              hipStream_t stream) {
  (void)in_sizes; (void)n_in; (void)out_size; (void)ws_size;
  const float* h = (const float*)d_in[0];
  const float* W = (const float*)d_in[1];
  const float* a = (const float*)d_in[2];
  float* out = (float*)d_out;

  // workspace carve-up (floats); total ~13.1 MB
  float* ws = (float*)d_ws;
  size_t off = 0;
  float* Wh    = ws + off; off += (size_t)NROW * F;   // 4 MB
  float* c     = ws + off; off += NROW;
  float* d     = ws + off; off += NROW;
  float* dsort = ws + off; off += NROW;
  float* E1    = ws + off; off += NROW;
  float* E2    = ws + off; off += NROW;
  float* M     = ws + off; off += 16;
  int*   perm  = (int*)(ws + off); off += NROW;
  float* Suf   = ws + off; off += (size_t)B * NK * ST; // 4.26 MB
  float* Pre   = ws + off; off += (size_t)B * NK * ST; // 4.26 MB

  k_wh      <<<NROW / 4, 256, 0, stream>>>(h, W, a, Wh, c, d);
  k_bmax    <<<B,        256, 0, stream>>>(d, M);
  k_ranksort<<<NROW / 4, 256, 0, stream>>>(d, M, dsort, perm, E1, E2);
  k_scan    <<<dim3(ST, B), 256, 0, stream>>>(Wh, perm, E1, E2, Suf, Pre);
  k_final   <<<NROW / 4, 256, 0, stream>>>(c, M, dsort, Suf, Pre, out);
}

// Round 2
// 109.965 us; speedup vs baseline: 1.2349x; 1.2349x over previous
//
#include <hip/hip_runtime.h>
#include <math.h>

// GAT forward, B=8, N=2048, F=64.
// e[b,i,j] = leakyrelu(c_i + d_j) is rank-structured; leakyrelu is piecewise
// linear with one breakpoint, so softmax(e)@Wh reduces per row to TWO
// threshold-set sums over j (d_j > -c_i vs <=). With d sorted per batch these
// are suffix/prefix scans: O(B*N*F) total instead of O(B*N^2*F).
//   m_i = g(c_i + max_j d_j)  (g monotone) -> analytic row max, exponents <= 0.

#define B 8
#define N 2048
#define F 64
#define NROW (B * N)      // 16384
#define NKP 2052          // 2049 scan boundaries padded to /4 for float4
#define ST 65             // 64 features + 1 denominator channel

__device__ __forceinline__ unsigned int ord32(float v) {
  unsigned int u = __float_as_uint(v);
  return (u & 0x80000000u) ? ~u : (u | 0x80000000u);
}

// ---- K1: Wh = h@W ; c = Wh@a_src ; d = Wh@a_dst ----------------------------
// Block=256 (4 waves), 16 rows/block. W column per lane in 64 VGPRs; h rows
// staged in LDS, consumed via broadcast float4 (no bpermute storm).
__global__ __launch_bounds__(256) void k_wh(const float* __restrict__ h,
                                            const float* __restrict__ W,
                                            const float* __restrict__ a,
                                            float* __restrict__ Wh,
                                            float* __restrict__ c,
                                            float* __restrict__ d) {
  __shared__ float hl[1024];                 // 16 rows x 64
  int t = threadIdx.x, lane = t & 63, wid = t >> 6;
  int blk = blockIdx.x;
  *(float4*)&hl[t * 4] = *(const float4*)&h[(size_t)blk * 1024 + t * 4];
  float wreg[64];
#pragma unroll
  for (int k = 0; k < 64; ++k) wreg[k] = W[k * 64 + lane];
  float as = a[lane], ad = a[64 + lane];
  __syncthreads();
#pragma unroll
  for (int rr = 0; rr < 4; ++rr) {
    int rl = wid * 4 + rr;
    int row = blk * 16 + rl;
    float acc = 0.f;
#pragma unroll
    for (int kk = 0; kk < 16; ++kk) {
      float4 hq = *(const float4*)&hl[rl * 64 + kk * 4];   // LDS broadcast
      acc = fmaf(hq.x, wreg[kk * 4 + 0], acc);
      acc = fmaf(hq.y, wreg[kk * 4 + 1], acc);
      acc = fmaf(hq.z, wreg[kk * 4 + 2], acc);
      acc = fmaf(hq.w, wreg[kk * 4 + 3], acc);
    }
    Wh[(size_t)row * 64 + lane] = acc;
    float ps = acc * as, pd = acc * ad;
#pragma unroll
    for (int off = 32; off > 0; off >>= 1) {
      ps += __shfl_xor(ps, off, 64);
      pd += __shfl_xor(pd, off, 64);
    }
    if (lane == 0) { c[row] = ps; d[row] = pd; }
  }
}

// ---- K2: fused rank-sort + batch-max + threshold-count ---------------------
// Wave per element j. One pass over d[b,:] yields: rank (comparison count with
// (value,index) tie-break -> exact permutation), batch max m, and
// kidx = #{d_j <= -c_row} (replaces k_final's binary search).
__global__ __launch_bounds__(256) void k_rank(const float* __restrict__ d,
                                              const float* __restrict__ c,
                                              float* __restrict__ E1,
                                              float* __restrict__ E2,
                                              int* __restrict__ perm,
                                              int* __restrict__ kidx,
                                              float* __restrict__ M) {
  int t = threadIdx.x, lane = t & 63, wid = t >> 6;
  int row = blockIdx.x * 4 + wid;
  int b = row >> 11, j = row & (N - 1);
  const float* db = d + b * N;
  float dj = db[j];                          // wave-uniform
  float thr = -c[row];
  unsigned long long kj = ((unsigned long long)ord32(dj) << 11) | (unsigned)j;
  int cnt = 0, cnt2 = 0;
  float m = -INFINITY;
#pragma unroll 8
  for (int it = 0; it < N / 64; ++it) {
    int jj = it * 64 + lane;
    float v = db[jj];
    unsigned long long kv = ((unsigned long long)ord32(v) << 11) | (unsigned)jj;
    cnt  += (kv < kj) ? 1 : 0;
    cnt2 += (v <= thr) ? 1 : 0;
    m = fmaxf(m, v);
  }
#pragma unroll
  for (int off = 32; off > 0; off >>= 1) {
    cnt  += __shfl_xor(cnt,  off, 64);
    cnt2 += __shfl_xor(cnt2, off, 64);
    m = fmaxf(m, __shfl_xor(m, off, 64));
  }
  if (lane == 0) {
    int r = b * N + cnt;
    E1[r]   = __expf(dj - m);                // <= 1
    E2[r]   = __expf(0.2f * (dj - m));       // <= 1
    perm[r] = j;
    kidx[row] = cnt2;
    if (j == 0) M[b] = m;
  }
}

// ---- K3: scans over sorted ranks -------------------------------------------
// Block per (channel o, batch b). Thread t owns ranks [8t, 8t+8). Shfl-based
// wave scans + one barrier for cross-wave bases. Output layout [b][o][k]
// (stride NKP) -> fully-coalesced float4 stores.
__global__ __launch_bounds__(256) void k_scan(const float* __restrict__ Wh,
                                              const int* __restrict__ perm,
                                              const float* __restrict__ E1,
                                              const float* __restrict__ E2,
                                              float* __restrict__ Suf,
                                              float* __restrict__ Pre) {
  __shared__ float wt1[4], wt2[4];
  int o = blockIdx.x, b = blockIdx.y;
  int t = threadIdx.x, lane = t & 63, wid = t >> 6;
  int r0 = t * 8;
  const float* Whb = Wh + (size_t)b * N * 64;
  const int* pb = perm + b * N;
  const float* e1 = E1 + b * N;
  const float* e2 = E2 + b * N;
  float x1[8], x2[8];
#pragma unroll
  for (int q = 0; q < 8; ++q) {
    int r = r0 + q;
    float val = 1.0f;
    if (o < 64) val = Whb[(size_t)pb[r] * 64 + o];
    x1[q] = e1[r] * val;
    x2[q] = e2[r] * val;
  }
  float lp[8], ss[8];
  float s2 = 0.f;
#pragma unroll
  for (int q = 0; q < 8; ++q) { s2 += x2[q]; lp[q] = s2; }
  float s1 = 0.f;
#pragma unroll
  for (int q = 7; q >= 0; --q) { s1 += x1[q]; ss[q] = s1; }
  // wave-level inclusive prefix (i2) and inclusive suffix (r1)
  float i2 = s2;
#pragma unroll
  for (int off = 1; off < 64; off <<= 1) {
    float v = __shfl_up(i2, off, 64);
    if (lane >= off) i2 += v;
  }
  float r1 = s1;
#pragma unroll
  for (int off = 1; off < 64; off <<= 1) {
    float v = __shfl_down(r1, off, 64);
    if (lane < 64 - off) r1 += v;
  }
  if (lane == 63) wt2[wid] = i2;             // wave totals
  if (lane == 0)  wt1[wid] = r1;
  __syncthreads();
  float base2 = 0.f, after1 = 0.f, tot2 = 0.f;
#pragma unroll
  for (int w = 0; w < 4; ++w) {
    float a2 = wt2[w], a1 = wt1[w];
    tot2 += a2;
    if (w < wid) base2 += a2;
    if (w > wid) after1 += a1;
  }
  float excl = base2 + (i2 - s2);            // exclusive prefix before r0
  float aftr = after1 + (r1 - s1);           // suffix strictly after r0+7
  float* Sb = Suf + ((size_t)b * ST + o) * NKP;
  float* Pb = Pre + ((size_t)b * ST + o) * NKP;
  float4 sv0 = { aftr + ss[0], aftr + ss[1], aftr + ss[2], aftr + ss[3] };
  float4 sv1 = { aftr + ss[4], aftr + ss[5], aftr + ss[6], aftr + ss[7] };
  float4 pv0 = { excl, excl + lp[0], excl + lp[1], excl + lp[2] };
  float4 pv1 = { excl + lp[3], excl + lp[4], excl + lp[5], excl + lp[6] };
  *(float4*)&Sb[r0]     = sv0;
  *(float4*)&Sb[r0 + 4] = sv1;
  *(float4*)&Pb[r0]     = pv0;
  *(float4*)&Pb[r0 + 4] = pv1;
  if (t == 255) { Sb[N] = 0.f; Pb[N] = tot2; }   // k = N boundary
}

// ---- K4: combine + ELU ------------------------------------------------------
__global__ __launch_bounds__(256) void k_final(const float* __restrict__ c,
                                               const float* __restrict__ M,
                                               const int* __restrict__ kidx,
                                               const float* __restrict__ Suf,
                                               const float* __restrict__ Pre,
                                               float* __restrict__ out) {
  int t = threadIdx.x, lane = t & 63, wid = t >> 6;
  int row = blockIdx.x * 4 + wid;
  int b = row >> 11;
  int k = kidx[row];
  float cpM = c[row] + M[b];
  float f1, f2;                              // exponents <= 0: no overflow
  if (cpM > 0.f) { f1 = 1.f;                 f2 = __expf(-0.8f * cpM); }
  else           { f1 = __expf(0.8f * cpM);  f2 = 1.f; }
  size_t basev = ((size_t)b * ST + lane) * NKP + k;
  size_t based = ((size_t)b * ST + 64)   * NKP + k;
  float S  = Suf[basev], P  = Pre[basev];
  float Sd = Suf[based], Pd = Pre[based];
  float v = (f1 * S + f2 * P) / (f1 * Sd + f2 * Pd);
  out[(size_t)row * 64 + lane] = (v > 0.f) ? v : expm1f(v);   // ELU alpha=1
}

// ---- launch -----------------------------------------------------------------
extern "C" void kernel_launch(void* const* d_in, const int* in_sizes, int n_in,
                              void* d_out, int out_size, void* d_ws, size_t ws_size,
                              hipStream_t stream) {
  (void)in_sizes; (void)n_in; (void)out_size; (void)ws_size;
  const float* h = (const float*)d_in[0];
  const float* W = (const float*)d_in[1];
  const float* a = (const float*)d_in[2];
  float* out = (float*)d_out;

  float* ws = (float*)d_ws;
  size_t off = 0;
  float* Wh   = ws + off; off += (size_t)NROW * F;        // 4 MB
  float* c    = ws + off; off += NROW;
  float* d    = ws + off; off += NROW;
  float* E1   = ws + off; off += NROW;
  float* E2   = ws + off; off += NROW;
  float* M    = ws + off; off += 16;
  int*   perm = (int*)(ws + off); off += NROW;
  int*   kidx = (int*)(ws + off); off += NROW;
  float* Suf  = ws + off; off += (size_t)B * ST * NKP;    // 4.07 MB
  float* Pre  = ws + off; off += (size_t)B * ST * NKP;    // 4.07 MB

  k_wh   <<<NROW / 16, 256, 0, stream>>>(h, W, a, Wh, c, d);
  k_rank <<<NROW / 4,  256, 0, stream>>>(d, c, E1, E2, perm, kidx, M);
  k_scan <<<dim3(ST, B), 256, 0, stream>>>(Wh, perm, E1, E2, Suf, Pre);
  k_final<<<NROW / 4,  256, 0, stream>>>(c, M, kidx, Suf, Pre, out);
}